// Round 1
// baseline (101.523 us; speedup 1.0000x reference)
//
#include <hip/hip_runtime.h>
#include <math.h>

#define NCLS 21
#define DD   256
#define HWPIX (512*512)          // 262144
#define HW2   (HWPIX/2)          // 131072  (float2 granularity)
#define EPSV  1e-6f

#define WT_STRIDE 24             // padded row stride (floats): 96 B, 16B-aligned rows
#define WT_FLOATS (DD*WT_STRIDE) // 6144 floats = 24 KB
#define THREADS 256
#define MAIN_BLOCKS (HW2/THREADS) // 512

// ---------------- kernel 0: fold w_norm into transposed weights ----------------
__global__ void prep_weights(const float* __restrict__ w,  // [NCLS][DD]
                             float* __restrict__ wt)       // [DD][WT_STRIDE]
{
    __shared__ float inv_wn[NCLS];
    int tid = threadIdx.x;
    int wave = tid >> 6, lane = tid & 63;
    for (int c = wave; c < NCLS; c += 4) {
        float s = 0.f;
        #pragma unroll
        for (int k = 0; k < 4; ++k) {
            float v = w[c*DD + lane + 64*k];
            s = fmaf(v, v, s);
        }
        #pragma unroll
        for (int off = 32; off; off >>= 1) s += __shfl_xor(s, off, 64);
        if (lane == 0) inv_wn[c] = 1.0f / fmaxf(sqrtf(s), EPSV);
    }
    __syncthreads();
    for (int i = tid; i < NCLS*DD; i += THREADS) {
        int c = i / DD, d = i - c*DD;
        wt[d*WT_STRIDE + c] = w[i] * inv_wn[c];
    }
}

// ---------------- kernel 1: fused per-pixel pass + block reduction ----------------
__global__ __launch_bounds__(THREADS)
void main_kernel(const float* __restrict__ yp,    // [NCLS][HWPIX]
                 const int*   __restrict__ ycrf,  // [HWPIX]
                 const int*   __restrict__ yret,  // [HWPIX]
                 const float* __restrict__ fm,    // [DD][HWPIX]
                 const float* __restrict__ wt,    // [DD][WT_STRIDE] (normalized, transposed)
                 float* __restrict__ partials)    // [MAIN_BLOCKS][4]
{
    __shared__ float lds_wt[WT_FLOATS];
    __shared__ float red[4][4];

    int tid = threadIdx.x;
    // stage normalized weights into LDS (24 KB)
    {
        const float4* src = (const float4*)wt;
        float4* dst = (float4*)lds_wt;
        #pragma unroll
        for (int i = 0; i < WT_FLOATS/4/THREADS; ++i)
            dst[i*THREADS + tid] = src[i*THREADS + tid];
    }
    __syncthreads();

    const int g = blockIdx.x * THREADS + tid;    // float2-pixel index
    const float2* fm2 = (const float2*)fm;
    const float2* yp2 = (const float2*)yp;
    const int2*   yc2 = (const int2*)ycrf;
    const int2*   yr2 = (const int2*)yret;

    float dot0[NCLS], dot1[NCLS];
    float nn0 = 0.f, nn1 = 0.f;
    #pragma unroll
    for (int c = 0; c < NCLS; ++c) { dot0[c] = 0.f; dot1[c] = 0.f; }

    // ---- dot products with normalized weights + feature norm ----
    for (int d = 0; d < DD; ++d) {
        float2 v = fm2[d*HW2 + g];
        float wreg[24];
        const float4* wr4 = (const float4*)&lds_wt[d*WT_STRIDE];
        #pragma unroll
        for (int i = 0; i < 6; ++i) ((float4*)wreg)[i] = wr4[i];  // 6x ds_read_b128 (broadcast)
        #pragma unroll
        for (int c = 0; c < NCLS; ++c) {
            dot0[c] = fmaf(v.x, wreg[c], dot0[c]);
            dot1[c] = fmaf(v.y, wreg[c], dot1[c]);
        }
        nn0 = fmaf(v.x, v.x, nn0);
        nn1 = fmaf(v.y, v.y, nn1);
    }

    const int2 yc = yc2[g], yr = yr2[g];

    // ---- corr / conf ----
    float inv_fn0 = 1.0f / fmaxf(sqrtf(nn0), EPSV);
    float inv_fn1 = 1.0f / fmaxf(sqrtf(nn1), EPSV);
    float cs0 = 0.f, cs1 = 0.f, cm0 = 0.f, cm1 = 0.f;  // cm init 0 == max(...,0)
    #pragma unroll
    for (int c = 0; c < NCLS; ++c) {
        float c0 = fmaf(dot0[c], inv_fn0, 1.0f);
        float c1 = fmaf(dot1[c], inv_fn1, 1.0f);
        cm0 = fmaxf(cm0, c0);
        cm1 = fmaxf(cm1, c1);
        cs0 = (yc.x == c) ? c0 : cs0;
        cs1 = (yc.y == c) ? c1 : cs1;
    }
    float r0 = cs0 / cm0, r1 = cs1 / cm1;
    float conf0 = r0 * r0, conf1 = r1 * r1;            // GAMMA = 2

    // ---- log-prob pass ----
    float slp0 = 0.f, slp1 = 0.f, lpc0 = 0.f, lpc1 = 0.f;
    #pragma unroll
    for (int c = 0; c < NCLS; ++c) {
        float2 p = yp2[c*HW2 + g];
        float l0 = __logf(p.x), l1 = __logf(p.y);
        slp0 += l0; slp1 += l1;
        lpc0 = (yc.x == c) ? l0 : lpc0;
        lpc1 = (yc.y == c) ? l1 : lpc1;
    }

    const bool s0 = (yc.x == yr.x), s1 = (yc.y == yr.y);
    float sl0 = s0 ? lpc0 : 0.f,  sl1 = s1 ? lpc1 : 0.f;
    float a_nce = sl0 + sl1;                                        // Σ s·logp_crf
    float a_dce = (s0 ? 1.f : 0.f) + (s1 ? 1.f : 0.f);              // Σ s
    float a_dw  = conf0 * ((float)NCLS - (s0 ? 1.f : 0.f))
                + conf1 * ((float)NCLS - (s1 ? 1.f : 0.f));         // Σ conf·(C-s)
    float a_nw  = conf0 * (slp0 - sl0) + conf1 * (slp1 - sl1);      // Σ conf·(Σlogp - s·logp_crf)

    // ---- block reduction ----
    #pragma unroll
    for (int off = 32; off; off >>= 1) {
        a_nce += __shfl_xor(a_nce, off, 64);
        a_dce += __shfl_xor(a_dce, off, 64);
        a_dw  += __shfl_xor(a_dw,  off, 64);
        a_nw  += __shfl_xor(a_nw,  off, 64);
    }
    int wave = tid >> 6, lane = tid & 63;
    if (lane == 0) { red[wave][0]=a_nce; red[wave][1]=a_dce; red[wave][2]=a_dw; red[wave][3]=a_nw; }
    __syncthreads();
    if (tid == 0) {
        #pragma unroll
        for (int i = 0; i < 4; ++i)
            partials[blockIdx.x*4 + i] = red[0][i] + red[1][i] + red[2][i] + red[3][i];
    }
}

// ---------------- kernel 2: final reduction + loss assembly ----------------
__global__ void finalize(const float* __restrict__ partials, float* __restrict__ out)
{
    __shared__ float red[4][4];
    int tid = threadIdx.x;
    float s[4] = {0.f, 0.f, 0.f, 0.f};
    for (int b = tid; b < MAIN_BLOCKS; b += THREADS) {
        #pragma unroll
        for (int i = 0; i < 4; ++i) s[i] += partials[b*4 + i];
    }
    #pragma unroll
    for (int off = 32; off; off >>= 1) {
        #pragma unroll
        for (int i = 0; i < 4; ++i) s[i] += __shfl_xor(s[i], off, 64);
    }
    int wave = tid >> 6, lane = tid & 63;
    if (lane == 0) { red[wave][0]=s[0]; red[wave][1]=s[1]; red[wave][2]=s[2]; red[wave][3]=s[3]; }
    __syncthreads();
    if (tid == 0) {
        float nce = red[0][0]+red[1][0]+red[2][0]+red[3][0];
        float dce = red[0][1]+red[1][1]+red[2][1]+red[3][1];
        float dw  = red[0][2]+red[1][2]+red[2][2]+red[3][2];
        float nw  = red[0][3]+red[1][3]+red[2][3]+red[3][3];
        float ce  = -nce / dce;
        float wce = -nw  / dw;
        out[0] = ce + 0.1f * wce;
        out[1] = ce;
        out[2] = wce;
    }
}

extern "C" void kernel_launch(void* const* d_in, const int* in_sizes, int n_in,
                              void* d_out, int out_size, void* d_ws, size_t ws_size,
                              hipStream_t stream) {
    const float* y_pred = (const float*)d_in[0];
    const int*   ycrf   = (const int*)d_in[1];
    const int*   yret   = (const int*)d_in[2];
    const float* fmap   = (const float*)d_in[3];
    const float* cw     = (const float*)d_in[4];
    float* out = (float*)d_out;

    float* wt       = (float*)d_ws;              // 24 KB
    float* partials = wt + WT_FLOATS;            // 512*4 floats = 8 KB

    prep_weights<<<1, THREADS, 0, stream>>>(cw, wt);
    main_kernel<<<MAIN_BLOCKS, THREADS, 0, stream>>>(y_pred, ycrf, yret, fmap, wt, partials);
    finalize<<<1, THREADS, 0, stream>>>(partials, out);
}

// Round 3
// 76.374 us; speedup vs baseline: 1.3293x; 1.3293x over previous
//
#include <hip/hip_runtime.h>
#include <math.h>

#define NCLS 21
#define DD   256
#define HWPIX (512*512)          // 262144
#define HW2   (HWPIX/2)          // 131072  (float2 granularity)
#define EPSV  1e-6f

#define WT_STRIDE 24             // padded row stride (floats): 96 B, 16B-aligned rows
#define WT_FLOATS (DD*WT_STRIDE) // 6144 floats = 24 KB
#define THREADS 256
#define MAIN_BLOCKS (HW2/THREADS) // 512
#define UND 8                    // d-loop unroll / prefetch depth

typedef float __attribute__((ext_vector_type(2))) f2;
typedef float __attribute__((ext_vector_type(4))) f4;
typedef int   __attribute__((ext_vector_type(2))) i2;

// ---------------- kernel 0: fold w_norm into transposed weights ----------------
__global__ void prep_weights(const float* __restrict__ w,  // [NCLS][DD]
                             float* __restrict__ wt)       // [DD][WT_STRIDE]
{
    __shared__ float inv_wn[NCLS];
    int tid = threadIdx.x;
    int wave = tid >> 6, lane = tid & 63;
    for (int c = wave; c < NCLS; c += 4) {
        float s = 0.f;
        #pragma unroll
        for (int k = 0; k < 4; ++k) {
            float v = w[c*DD + lane + 64*k];
            s = fmaf(v, v, s);
        }
        #pragma unroll
        for (int off = 32; off; off >>= 1) s += __shfl_xor(s, off, 64);
        if (lane == 0) inv_wn[c] = 1.0f / fmaxf(sqrtf(s), EPSV);
    }
    __syncthreads();
    for (int i = tid; i < NCLS*DD; i += THREADS) {
        int c = i / DD, d = i - c*DD;
        wt[d*WT_STRIDE + c] = w[i] * inv_wn[c];
    }
}

// ---------------- kernel 1: fused per-pixel pass + block reduction ----------------
__global__ __launch_bounds__(THREADS, 2)
void main_kernel(const float* __restrict__ yp,    // [NCLS][HWPIX]
                 const int*   __restrict__ ycrf,  // [HWPIX]
                 const int*   __restrict__ yret,  // [HWPIX]
                 const float* __restrict__ fm,    // [DD][HWPIX]
                 const float* __restrict__ wt,    // [DD][WT_STRIDE] (normalized, transposed)
                 float* __restrict__ partials)    // [MAIN_BLOCKS][4]
{
    __shared__ float lds_wt[WT_FLOATS];
    __shared__ float red[4][4];

    int tid = threadIdx.x;
    // stage normalized weights into LDS (24 KB)
    {
        const f4* src = (const f4*)wt;
        f4* dst = (f4*)lds_wt;
        #pragma unroll
        for (int i = 0; i < WT_FLOATS/4/THREADS; ++i)
            dst[i*THREADS + tid] = src[i*THREADS + tid];
    }
    __syncthreads();

    const int g = blockIdx.x * THREADS + tid;    // float2-pixel index
    const f2* fm2 = (const f2*)fm;
    const f2* yp2 = (const f2*)yp;
    const i2* yc2 = (const i2*)ycrf;
    const i2* yr2 = (const i2*)yret;

    float dot0[NCLS], dot1[NCLS];
    float nn0 = 0.f, nn1 = 0.f;
    #pragma unroll
    for (int c = 0; c < NCLS; ++c) { dot0[c] = 0.f; dot1[c] = 0.f; }

    // ---- dot products with normalized weights + feature norm ----
    // software-pipelined: prefetch next UND feature values while computing current
    f2 v[UND];
    #pragma unroll
    for (int u = 0; u < UND; ++u)
        v[u] = __builtin_nontemporal_load(&fm2[u*HW2 + g]);

    for (int d0 = 0; d0 < DD; d0 += UND) {
        f2 nv[UND];
        if (d0 + UND < DD) {
            #pragma unroll
            for (int u = 0; u < UND; ++u)
                nv[u] = __builtin_nontemporal_load(&fm2[(d0 + UND + u)*HW2 + g]);
        }
        #pragma unroll
        for (int u = 0; u < UND; ++u) {
            float wreg[24];
            const f4* wr4 = (const f4*)&lds_wt[(d0 + u)*WT_STRIDE];
            #pragma unroll
            for (int i = 0; i < 6; ++i) ((f4*)wreg)[i] = wr4[i];  // broadcast ds_read_b128
            float vx = v[u].x, vy = v[u].y;
            #pragma unroll
            for (int c = 0; c < NCLS; ++c) {
                dot0[c] = fmaf(vx, wreg[c], dot0[c]);
                dot1[c] = fmaf(vy, wreg[c], dot1[c]);
            }
            nn0 = fmaf(vx, vx, nn0);
            nn1 = fmaf(vy, vy, nn1);
        }
        #pragma unroll
        for (int u = 0; u < UND; ++u) v[u] = nv[u];
    }

    const i2 yc = yc2[g], yr = yr2[g];

    // ---- corr / conf ----
    float inv_fn0 = 1.0f / fmaxf(sqrtf(nn0), EPSV);
    float inv_fn1 = 1.0f / fmaxf(sqrtf(nn1), EPSV);
    float cs0 = 0.f, cs1 = 0.f, cm0 = 0.f, cm1 = 0.f;  // cm init 0 == max(...,0)
    #pragma unroll
    for (int c = 0; c < NCLS; ++c) {
        float c0 = fmaf(dot0[c], inv_fn0, 1.0f);
        float c1 = fmaf(dot1[c], inv_fn1, 1.0f);
        cm0 = fmaxf(cm0, c0);
        cm1 = fmaxf(cm1, c1);
        cs0 = (yc.x == c) ? c0 : cs0;
        cs1 = (yc.y == c) ? c1 : cs1;
    }
    float r0 = cs0 / cm0, r1 = cs1 / cm1;
    float conf0 = r0 * r0, conf1 = r1 * r1;            // GAMMA = 2

    // ---- log-prob pass (21 independent loads, issued together) ----
    f2 p[NCLS];
    #pragma unroll
    for (int c = 0; c < NCLS; ++c)
        p[c] = __builtin_nontemporal_load(&yp2[c*HW2 + g]);

    float slp0 = 0.f, slp1 = 0.f, lpc0 = 0.f, lpc1 = 0.f;
    #pragma unroll
    for (int c = 0; c < NCLS; ++c) {
        float l0 = __logf(p[c].x), l1 = __logf(p[c].y);
        slp0 += l0; slp1 += l1;
        lpc0 = (yc.x == c) ? l0 : lpc0;
        lpc1 = (yc.y == c) ? l1 : lpc1;
    }

    const bool s0 = (yc.x == yr.x), s1 = (yc.y == yr.y);
    float sl0 = s0 ? lpc0 : 0.f,  sl1 = s1 ? lpc1 : 0.f;
    float a_nce = sl0 + sl1;                                        // Σ s·logp_crf
    float a_dce = (s0 ? 1.f : 0.f) + (s1 ? 1.f : 0.f);              // Σ s
    float a_dw  = conf0 * ((float)NCLS - (s0 ? 1.f : 0.f))
                + conf1 * ((float)NCLS - (s1 ? 1.f : 0.f));         // Σ conf·(C-s)
    float a_nw  = conf0 * (slp0 - sl0) + conf1 * (slp1 - sl1);      // Σ conf·(Σlogp - s·logp_crf)

    // ---- block reduction ----
    #pragma unroll
    for (int off = 32; off; off >>= 1) {
        a_nce += __shfl_xor(a_nce, off, 64);
        a_dce += __shfl_xor(a_dce, off, 64);
        a_dw  += __shfl_xor(a_dw,  off, 64);
        a_nw  += __shfl_xor(a_nw,  off, 64);
    }
    int wave = tid >> 6, lane = tid & 63;
    if (lane == 0) { red[wave][0]=a_nce; red[wave][1]=a_dce; red[wave][2]=a_dw; red[wave][3]=a_nw; }
    __syncthreads();
    if (tid == 0) {
        #pragma unroll
        for (int i = 0; i < 4; ++i)
            partials[blockIdx.x*4 + i] = red[0][i] + red[1][i] + red[2][i] + red[3][i];
    }
}

// ---------------- kernel 2: final reduction + loss assembly ----------------
__global__ void finalize(const float* __restrict__ partials, float* __restrict__ out)
{
    __shared__ float red[4][4];
    int tid = threadIdx.x;
    float s[4] = {0.f, 0.f, 0.f, 0.f};
    for (int b = tid; b < MAIN_BLOCKS; b += THREADS) {
        #pragma unroll
        for (int i = 0; i < 4; ++i) s[i] += partials[b*4 + i];
    }
    #pragma unroll
    for (int off = 32; off; off >>= 1) {
        #pragma unroll
        for (int i = 0; i < 4; ++i) s[i] += __shfl_xor(s[i], off, 64);
    }
    int wave = tid >> 6, lane = tid & 63;
    if (lane == 0) { red[wave][0]=s[0]; red[wave][1]=s[1]; red[wave][2]=s[2]; red[wave][3]=s[3]; }
    __syncthreads();
    if (tid == 0) {
        float nce = red[0][0]+red[1][0]+red[2][0]+red[3][0];
        float dce = red[0][1]+red[1][1]+red[2][1]+red[3][1];
        float dw  = red[0][2]+red[1][2]+red[2][2]+red[3][2];
        float nw  = red[0][3]+red[1][3]+red[2][3]+red[3][3];
        float ce  = -nce / dce;
        float wce = -nw  / dw;
        out[0] = ce + 0.1f * wce;
        out[1] = ce;
        out[2] = wce;
    }
}

extern "C" void kernel_launch(void* const* d_in, const int* in_sizes, int n_in,
                              void* d_out, int out_size, void* d_ws, size_t ws_size,
                              hipStream_t stream) {
    const float* y_pred = (const float*)d_in[0];
    const int*   ycrf   = (const int*)d_in[1];
    const int*   yret   = (const int*)d_in[2];
    const float* fmap   = (const float*)d_in[3];
    const float* cw     = (const float*)d_in[4];
    float* out = (float*)d_out;

    float* wt       = (float*)d_ws;              // 24 KB
    float* partials = wt + WT_FLOATS;            // 512*4 floats = 8 KB

    prep_weights<<<1, THREADS, 0, stream>>>(cw, wt);
    main_kernel<<<MAIN_BLOCKS, THREADS, 0, stream>>>(y_pred, ycrf, yret, fmap, wt, partials);
    finalize<<<1, THREADS, 0, stream>>>(partials, out);
}

// Round 4
// 75.367 us; speedup vs baseline: 1.3471x; 1.0134x over previous
//
#include <hip/hip_runtime.h>
#include <math.h>

#define NCLS 21
#define DD   256
#define HWPIX (512*512)          // 262144 pixels
#define EPSV  1e-6f

#define WT_STRIDE 24             // padded row stride (floats): 96 B, 16B-aligned rows
#define WT_FLOATS (DD*WT_STRIDE) // 6144 floats = 24 KB
#define THREADS 256
#define MAIN_BLOCKS (HWPIX/THREADS) // 1024  (one float per lane)
#define UND 8                    // d-loop unroll / prefetch depth

typedef float __attribute__((ext_vector_type(4))) f4;

// ---------------- kernel 0: fold w_norm into transposed weights ----------------
__global__ void prep_weights(const float* __restrict__ w,  // [NCLS][DD]
                             float* __restrict__ wt)       // [DD][WT_STRIDE]
{
    __shared__ float inv_wn[NCLS];
    int tid = threadIdx.x;
    int wave = tid >> 6, lane = tid & 63;
    for (int c = wave; c < NCLS; c += 4) {
        float s = 0.f;
        #pragma unroll
        for (int k = 0; k < 4; ++k) {
            float v = w[c*DD + lane + 64*k];
            s = fmaf(v, v, s);
        }
        #pragma unroll
        for (int off = 32; off; off >>= 1) s += __shfl_xor(s, off, 64);
        if (lane == 0) inv_wn[c] = 1.0f / fmaxf(sqrtf(s), EPSV);
    }
    __syncthreads();
    for (int i = tid; i < DD*WT_STRIDE; i += THREADS) {
        int d = i / WT_STRIDE, c = i - d*WT_STRIDE;
        wt[i] = (c < NCLS) ? w[c*DD + d] * inv_wn[c] : 0.f;
    }
}

// ---------------- kernel 1: fused per-pixel pass + block reduction ----------------
// No LDS in the hot loop: weight rows are read with wave-uniform float4 loads
// (24 KB table stays L1-resident; uniform address -> single request + broadcast).
__global__ __launch_bounds__(THREADS, 4)
void main_kernel(const float* __restrict__ yp,    // [NCLS][HWPIX]
                 const int*   __restrict__ ycrf,  // [HWPIX]
                 const int*   __restrict__ yret,  // [HWPIX]
                 const float* __restrict__ fm,    // [DD][HWPIX]
                 const float* __restrict__ wt,    // [DD][WT_STRIDE] (normalized, transposed)
                 float* __restrict__ partials)    // [MAIN_BLOCKS][4]
{
    __shared__ float red[4][4];

    const int tid = threadIdx.x;
    const int g = blockIdx.x * THREADS + tid;    // pixel index

    float dot[NCLS];
    float nn = 0.f;
    #pragma unroll
    for (int c = 0; c < NCLS; ++c) dot[c] = 0.f;

    // ---- dot products with normalized weights + feature norm ----
    // software-pipelined: prefetch next UND feature values while computing current
    float v[UND];
    #pragma unroll
    for (int u = 0; u < UND; ++u)
        v[u] = __builtin_nontemporal_load(&fm[u*HWPIX + g]);

    for (int d0 = 0; d0 < DD; d0 += UND) {
        float nv[UND];
        if (d0 + UND < DD) {
            #pragma unroll
            for (int u = 0; u < UND; ++u)
                nv[u] = __builtin_nontemporal_load(&fm[(d0 + UND + u)*HWPIX + g]);
        }
        #pragma unroll
        for (int u = 0; u < UND; ++u) {
            // wave-uniform weight row read (96 B): 6x dwordx4, L1 broadcast
            const f4* wr = (const f4*)(wt + (d0 + u)*WT_STRIDE);
            float wreg[24];
            #pragma unroll
            for (int i = 0; i < 6; ++i) ((f4*)wreg)[i] = wr[i];
            float vx = v[u];
            #pragma unroll
            for (int c = 0; c < NCLS; ++c)
                dot[c] = fmaf(vx, wreg[c], dot[c]);
            nn = fmaf(vx, vx, nn);
        }
        #pragma unroll
        for (int u = 0; u < UND; ++u) v[u] = nv[u];
    }

    const int yc = ycrf[g], yr = yret[g];

    // ---- corr / conf ----
    float inv_fn = 1.0f / fmaxf(sqrtf(nn), EPSV);
    float cs = 0.f, cm = 0.f;                    // cm init 0 == max(...,0)
    #pragma unroll
    for (int c = 0; c < NCLS; ++c) {
        float cv = fmaf(dot[c], inv_fn, 1.0f);
        cm = fmaxf(cm, cv);
        cs = (yc == c) ? cv : cs;
    }
    float r = cs / cm;
    float conf = r * r;                          // GAMMA = 2

    // ---- log-prob pass (21 independent loads, issued together) ----
    float p[NCLS];
    #pragma unroll
    for (int c = 0; c < NCLS; ++c)
        p[c] = __builtin_nontemporal_load(&yp[c*HWPIX + g]);

    float slp = 0.f, lpc = 0.f;
    #pragma unroll
    for (int c = 0; c < NCLS; ++c) {
        float l = __logf(p[c]);
        slp += l;
        lpc = (yc == c) ? l : lpc;
    }

    const bool s = (yc == yr);
    float sl = s ? lpc : 0.f;
    float a_nce = sl;                                        // Σ s·logp_crf
    float a_dce = s ? 1.f : 0.f;                             // Σ s
    float a_dw  = conf * ((float)NCLS - (s ? 1.f : 0.f));    // Σ conf·(C-s)
    float a_nw  = conf * (slp - sl);                         // Σ conf·(Σlogp - s·logp_crf)

    // ---- block reduction ----
    #pragma unroll
    for (int off = 32; off; off >>= 1) {
        a_nce += __shfl_xor(a_nce, off, 64);
        a_dce += __shfl_xor(a_dce, off, 64);
        a_dw  += __shfl_xor(a_dw,  off, 64);
        a_nw  += __shfl_xor(a_nw,  off, 64);
    }
    int wave = tid >> 6, lane = tid & 63;
    if (lane == 0) { red[wave][0]=a_nce; red[wave][1]=a_dce; red[wave][2]=a_dw; red[wave][3]=a_nw; }
    __syncthreads();
    if (tid == 0) {
        #pragma unroll
        for (int i = 0; i < 4; ++i)
            partials[blockIdx.x*4 + i] = red[0][i] + red[1][i] + red[2][i] + red[3][i];
    }
}

// ---------------- kernel 2: final reduction + loss assembly ----------------
__global__ void finalize(const float* __restrict__ partials, float* __restrict__ out)
{
    __shared__ float red[4][4];
    int tid = threadIdx.x;
    float s[4] = {0.f, 0.f, 0.f, 0.f};
    for (int b = tid; b < MAIN_BLOCKS; b += THREADS) {
        #pragma unroll
        for (int i = 0; i < 4; ++i) s[i] += partials[b*4 + i];
    }
    #pragma unroll
    for (int off = 32; off; off >>= 1) {
        #pragma unroll
        for (int i = 0; i < 4; ++i) s[i] += __shfl_xor(s[i], off, 64);
    }
    int wave = tid >> 6, lane = tid & 63;
    if (lane == 0) { red[wave][0]=s[0]; red[wave][1]=s[1]; red[wave][2]=s[2]; red[wave][3]=s[3]; }
    __syncthreads();
    if (tid == 0) {
        float nce = red[0][0]+red[1][0]+red[2][0]+red[3][0];
        float dce = red[0][1]+red[1][1]+red[2][1]+red[3][1];
        float dw  = red[0][2]+red[1][2]+red[2][2]+red[3][2];
        float nw  = red[0][3]+red[1][3]+red[2][3]+red[3][3];
        float ce  = -nce / dce;
        float wce = -nw  / dw;
        out[0] = ce + 0.1f * wce;
        out[1] = ce;
        out[2] = wce;
    }
}

extern "C" void kernel_launch(void* const* d_in, const int* in_sizes, int n_in,
                              void* d_out, int out_size, void* d_ws, size_t ws_size,
                              hipStream_t stream) {
    const float* y_pred = (const float*)d_in[0];
    const int*   ycrf   = (const int*)d_in[1];
    const int*   yret   = (const int*)d_in[2];
    const float* fmap   = (const float*)d_in[3];
    const float* cw     = (const float*)d_in[4];
    float* out = (float*)d_out;

    float* wt       = (float*)d_ws;              // 24 KB
    float* partials = wt + WT_FLOATS;            // 1024*4 floats = 16 KB

    prep_weights<<<1, THREADS, 0, stream>>>(cw, wt);
    main_kernel<<<MAIN_BLOCKS, THREADS, 0, stream>>>(y_pred, ycrf, yret, fmap, wt, partials);
    finalize<<<1, THREADS, 0, stream>>>(partials, out);
}